// Round 7
// baseline (240.361 us; speedup 1.0000x reference)
//
#include <hip/hip_runtime.h>

// AttentionMatcher R13b: resubmission of R13 (previous round's bench died
// with "MI355X container failed twice" — infra error, no kernel verdict).
// Audit found no hang/fault path: barriers wave-uniform, fixed trip count,
// SS coverage complete, register (m,l) copies provably identical.
//
// R13: full-K QK waves + register-resident (m,l).
// R12 post-mortem: halving barriers gained only 2us -> chain latency, not
// barrier count, dominates. The chain's serial LDS hops came from (a) kh
// K-split forcing a 2-plane SS combine in softmax, (b) m/l state in LDS
// (MS read + LS rmw ~240cyc serial). R13: QK waves = (jt, qh) with FULL
// K=256 per accumulator -> SS is single-plane, complete at MFMA output;
// softmax reads 2xfloat4 (no adds); SS writes halve. m/l live in registers
// (4 threads/row keep identical copies; mapping is tile-invariant).
// Costs: B-frags double (Bc[8]+Bn[8], +32 VGPR ~210 total, fits 2-wave
// budget 256) and Mh read 2x from L2 (L2 ~25% utilized - free).
// Pipeline (1 barrier/tile), nspl=4, bounds(256,2) unchanged from R12.
// out = gate * softmax(N M^T, diag<-0) M + (1-gate) * N,  n=8192, d=256, fp32.
//
// ws: MhG [n][256] fp16 row-major          (QK B-plane)
//     MtG [n/32 tiles][256 d][32 j] fp16   (PV B-plane, transposed tile-major)
//     Ofp 3 fp16 partial O planes (splits 1..3); split-0 partial f32 in d_out
//     MLm/MLl [4][n] f32 running max / sum per split.

constexpr int EMBED = 256;
constexpr int BQ = 64;
constexpr int BJ = 32;
constexpr int NT = 256;

constexpr int SS_OFF = 0;            // 2 buf x (64 x 36) f32 = 9216 B each
constexpr int SS_BUF = 9216;
constexpr int PH_OFF = 18432;        // 2 buf x 64 x 80 B
constexpr int PH_BUF = 5120;
constexpr int AS_OFF = 28672;        // 2 buf x 256 B
constexpr int AS_BUF = 256;
constexpr int LDS_SZ = 29184;        // x2 blocks/CU = 58.4 KB (<160)

typedef _Float16 half8 __attribute__((ext_vector_type(8)));
typedef float f32x4 __attribute__((ext_vector_type(4)));
typedef short short8v __attribute__((ext_vector_type(8)));

static __device__ __forceinline__ f32x4 mfma16(half8 a, half8 b, f32x4 c) {
    return __builtin_amdgcn_mfma_f32_16x16x32_f16(a, b, c, 0, 0, 0);
}
static __device__ __forceinline__ short f2h(float x) {
    return (short)__builtin_bit_cast(unsigned short, (_Float16)x);
}

// ---------- prep: fp16 row plane + fp16 transposed tile plane ----------
__global__ void prep(const float* __restrict__ M,
                     short* __restrict__ MhG, short* __restrict__ MtG) {
    __shared__ float L[16 * 260];
    const int r0 = blockIdx.x * 16;            // 16 M-rows per block
    const int t = threadIdx.x;
    const int pj = t >> 4, pc = (t & 15) * 16;
    {
        const float* src = M + (size_t)(r0 + pj) * EMBED + pc;
        float4 v[4];
        #pragma unroll
        for (int i = 0; i < 4; ++i) v[i] = ((const float4*)src)[i];
        short* hd = MhG + (size_t)(r0 + pj) * EMBED + pc;
        #pragma unroll
        for (int i = 0; i < 2; ++i) {
            float4 a = v[2 * i], b = v[2 * i + 1];
            short8v h;
            h[0]=f2h(a.x); h[1]=f2h(a.y); h[2]=f2h(a.z); h[3]=f2h(a.w);
            h[4]=f2h(b.x); h[5]=f2h(b.y); h[6]=f2h(b.z); h[7]=f2h(b.w);
            *(short8v*)(hd + 8 * i) = h;
        }
        #pragma unroll
        for (int i = 0; i < 4; ++i)
            *(float4*)(L + pj * 260 + pc + 4 * i) = v[i];
    }
    __syncthreads();
    {
        const int d = t;                        // 0..255
        const int tile = r0 >> 5, jh = (r0 >> 4) & 1;
        short* dst = MtG + (size_t)tile * (BJ * EMBED) + d * BJ + jh * 16;
        #pragma unroll
        for (int g2 = 0; g2 < 2; ++g2) {
            short8v w;
            #pragma unroll
            for (int e = 0; e < 8; ++e) w[e] = f2h(L[(g2 * 8 + e) * 260 + d]);
            *(short8v*)(dst + g2 * 8) = w;
        }
    }
}

// ---------- main split-j flash kernel: full-K waves, 1 barrier/tile ----------
__launch_bounds__(NT, 2)
__global__ void attn(const short* __restrict__ MhG, const short* __restrict__ MtG,
                     const float* __restrict__ Ng, const int* __restrict__ iseval_p,
                     float* __restrict__ O0out, short* __restrict__ Ofp,
                     float* __restrict__ MLm, float* __restrict__ MLl, int n)
{
    __shared__ __align__(16) char smem[LDS_SZ];

    const int t = threadIdx.x, lane = t & 63, wave = t >> 6;
    const int quad = lane >> 4, mn = lane & 15;
    // XCD swizzle: bid%8 -> XCD; all 64 blocks on an XCD share one split s.
    const int bid = blockIdx.x;
    const int s  = (bid & 7) >> 1;               // split 0..3
    const int qb = ((bid >> 3) << 1) | (bid & 1);// 0..127
    const int q0 = qb * BQ;
    const int jbase = s * (n >> 2);
    const int jb32 = jbase / BJ;
    const int ntiles = (n >> 2) / BJ;            // 64
    const int iseval = *iseval_p;
    const int jt = wave & 1, qh = wave >> 1;     // QK roles: j-tile, q-half (full K)
    const int dq = wave;                         // PV d-quarter
    const int sq = t >> 2, sh = t & 3;           // softmax roles

    // ---- Q fragments fp16 (A-layout): this wave's 2 q-tiles, FULL K ----
    half8 Qf[2][8];
    #pragma unroll
    for (int qi = 0; qi < 2; ++qi) {
        const float* np = Ng + (size_t)(q0 + (qh * 2 + qi) * 16 + mn) * EMBED;
        #pragma unroll
        for (int kk = 0; kk < 8; ++kk) {
            const float* p = np + kk * 32 + quad * 8;
            float4 a = *(const float4*)p, b = *(const float4*)(p + 4);
            half8 h;
            h[0]=(_Float16)a.x; h[1]=(_Float16)a.y; h[2]=(_Float16)a.z; h[3]=(_Float16)a.w;
            h[4]=(_Float16)b.x; h[5]=(_Float16)b.y; h[6]=(_Float16)b.z; h[7]=(_Float16)b.w;
            Qf[qi][kk] = h;
        }
    }

    f32x4 O[4][4];
    #pragma unroll
    for (int qi = 0; qi < 4; ++qi)
        #pragma unroll
        for (int dt = 0; dt < 4; ++dt) O[qi][dt] = (f32x4){0.f, 0.f, 0.f, 0.f};

    // QK B base: row j = jbase + tile*BJ + jt*16 + mn, full K cols (quad*8 lane slice)
    const short* mhb0 = MhG + (size_t)(jbase + jt * 16 + mn) * EMBED + quad * 8;
    half8 Bc[8], Bn[8], Mtf[4];
    #pragma unroll
    for (int kk = 0; kk < 8; ++kk) Bc[kk] = *(const half8*)(mhb0 + kk * 32);

    float m_reg = -1e30f, l_reg = 0.f;   // running max/sum for row sq (4 copies)

    // Pipelined loop: iter tt does QK(tt) || softmax(tt-1), barrier, PV(tt-1).
    for (int tt = 0; tt <= ntiles; ++tt) {
        const int bw = tt & 1;        // SS buffer written by QK(tt)
        const int br = bw ^ 1;        // buffer of tile tt-1 (valid for tt>0)

        // --- Mt prefetch for PV(tt-1): consumed after the barrier ---
        if (tt > 0) {
            const short* mtb = MtG + (size_t)(jb32 + (tt - 1)) * (BJ * EMBED);
            #pragma unroll
            for (int dt = 0; dt < 4; ++dt)
                Mtf[dt] = *(const half8*)(mtb + (dq * 64 + dt * 16 + mn) * BJ + quad * 8);
        }

        // --- QK^T(tt): 2 q-tiles x this wave's j-tile, K=256 -> SS[bw] ---
        if (tt < ntiles) {
            f32x4 a0 = (f32x4){0,0,0,0}, a1 = (f32x4){0,0,0,0};
            #pragma unroll
            for (int kk = 0; kk < 8; ++kk) {
                half8 bf = Bc[kk];
                a0 = mfma16(Qf[0][kk], bf, a0);
                a1 = mfma16(Qf[1][kk], bf, a1);
            }
            float* ssp = (float*)(smem + SS_OFF + bw * SS_BUF);
            const int rb = qh * 32;
            #pragma unroll
            for (int r = 0; r < 4; ++r) {
                ssp[(rb +      quad * 4 + r) * 36 + jt * 16 + mn] = a0[r];
                ssp[(rb + 16 + quad * 4 + r) * 36 + jt * 16 + mn] = a1[r];
            }
        }

        // --- B-fragment prefetch for QK(tt+1) ---
        if (tt + 1 < ntiles) {
            const short* nb = mhb0 + (size_t)(tt + 1) * (BJ * EMBED);
            #pragma unroll
            for (int kk = 0; kk < 8; ++kk) Bn[kk] = *(const half8*)(nb + kk * 32);
        }

        // --- online softmax(tt-1): thread (sq, sh) owns j = 8sh..8sh+7 ---
        if (tt > 0) {
            const int j0g = jbase + (tt - 1) * BJ;
            const float* p0 = (const float*)(smem + SS_OFF + br * SS_BUF) + sq * 36 + 8 * sh;
            float4 sa = *(const float4*)p0;
            float4 sb = *(const float4*)(p0 + 4);
            float sv[8] = {sa.x, sa.y, sa.z, sa.w, sb.x, sb.y, sb.z, sb.w};
            const int qg = q0 + sq;
            if (iseval) {
                if (qg == 0) {
                    #pragma unroll
                    for (int i = 0; i < 8; ++i) sv[i] = 0.f;
                }
            } else {
                int dj = qg - j0g - 8 * sh;
                #pragma unroll
                for (int i = 0; i < 8; ++i) if (dj == i) sv[i] = 0.f;
            }
            float mx = sv[0];
            #pragma unroll
            for (int i = 1; i < 8; ++i) mx = fmaxf(mx, sv[i]);
            mx = fmaxf(mx, __shfl_xor(mx, 1));
            mx = fmaxf(mx, __shfl_xor(mx, 2));
            float m_new = fmaxf(m_reg, mx);
            float alpha = __expf(m_reg - m_new);
            float p[8], ps = 0.f;
            #pragma unroll
            for (int i = 0; i < 8; ++i) { p[i] = __expf(sv[i] - m_new); ps += p[i]; }
            ps += __shfl_xor(ps, 1);
            ps += __shfl_xor(ps, 2);
            m_reg = m_new;
            l_reg = l_reg * alpha + ps;          // identical in all 4 sh-copies
            if (sh == 0)
                ((float*)(smem + AS_OFF + br * AS_BUF))[sq] = alpha;
            half8 ph;
            #pragma unroll
            for (int i = 0; i < 8; ++i) ph[i] = (_Float16)p[i];
            *(half8*)(smem + PH_OFF + br * PH_BUF + sq * 80 + sh * 16) = ph;
        }

        __syncthreads();   // SS[bw] (next softmax) + PH/AS[br] (PV) visible

        // --- PV(tt-1): 4 q-tiles x this wave's 4 d-tiles, K=32 ---
        if (tt > 0) {
            #pragma unroll
            for (int qi = 0; qi < 4; ++qi) {
                half8 pf = *(const half8*)(smem + PH_OFF + br * PH_BUF + (qi * 16 + mn) * 80 + quad * 16);
                f32x4 al = *(const f32x4*)((const float*)(smem + AS_OFF + br * AS_BUF) + qi * 16 + quad * 4);
                #pragma unroll
                for (int dt = 0; dt < 4; ++dt) {
                    f32x4 o = O[qi][dt];
                    o[0] *= al[0]; o[1] *= al[1]; o[2] *= al[2]; o[3] *= al[3];
                    O[qi][dt] = mfma16(pf, Mtf[dt], o);
                }
            }
        }

        #pragma unroll
        for (int kk = 0; kk < 8; ++kk) Bc[kk] = Bn[kk];
        // SS[bw] reread by softmax(tt) in iter tt+1 BEFORE barrier(tt+1);
        // QK(tt+2) rewrites it after barrier(tt+1). Safe.
        // PH/AS[br] rewrite at softmax(tt+1) in iter tt+2, after barrier(tt+1)
        // which follows PV(tt-1). Safe.
    }

    // ---- epilogue: partial O + (m,l) per split ----
    if (s == 0) {
        #pragma unroll
        for (int qi = 0; qi < 4; ++qi)
            #pragma unroll
            for (int dt = 0; dt < 4; ++dt) {
                int col = dq * 64 + dt * 16 + mn;
                #pragma unroll
                for (int r = 0; r < 4; ++r)
                    O0out[(size_t)(q0 + qi * 16 + quad * 4 + r) * EMBED + col] = O[qi][dt][r];
            }
    } else {
        short* dst = Ofp + (size_t)(s - 1) * n * EMBED;
        #pragma unroll
        for (int qi = 0; qi < 4; ++qi)
            #pragma unroll
            for (int dt = 0; dt < 4; ++dt) {
                int col = dq * 64 + dt * 16 + mn;
                #pragma unroll
                for (int r = 0; r < 4; ++r)
                    dst[(size_t)(q0 + qi * 16 + quad * 4 + r) * EMBED + col] = f2h(O[qi][dt][r]);
            }
    }
    if (sh == 0) {                     // one writer per q-row (sq = 0..63)
        MLm[s * n + q0 + sq] = m_reg;
        MLl[s * n + q0 + sq] = l_reg;
    }
}

// ---------- combine 4 partials + gate + blend ----------
__global__ void combine4(const float* __restrict__ O0, const short* __restrict__ Ofp,
                         const float* __restrict__ MLm, const float* __restrict__ MLl,
                         const float* __restrict__ Ng, const float* __restrict__ Wg,
                         const float* __restrict__ bg, const float* __restrict__ gb,
                         float* __restrict__ out, int n)
{
    const int t = threadIdx.x;
    const int row = blockIdx.x * 16 + (t >> 4);
    const int c = t & 15;
    float ms[4], ls[4];
    #pragma unroll
    for (int k = 0; k < 4; ++k) { ms[k] = MLm[k * n + row]; ls[k] = MLl[k * n + row]; }
    float m = fmaxf(fmaxf(ms[0], ms[1]), fmaxf(ms[2], ms[3]));
    float w[4], lsum = 0.f;
    #pragma unroll
    for (int k = 0; k < 4; ++k) { w[k] = __expf(ms[k] - m); lsum += w[k] * ls[k]; }
    float linv = 1.f / lsum;

    float acc[16];
    {
        const float4* o0 = (const float4*)(O0 + (size_t)row * EMBED + c * 16);
        #pragma unroll
        for (int i = 0; i < 4; ++i) {
            float4 v = o0[i];
            acc[4*i+0] = w[0] * v.x; acc[4*i+1] = w[0] * v.y;
            acc[4*i+2] = w[0] * v.z; acc[4*i+3] = w[0] * v.w;
        }
    }
    #pragma unroll
    for (int k = 1; k < 4; ++k) {
        const short* op = Ofp + (size_t)(k - 1) * n * EMBED + (size_t)row * EMBED + c * 16;
        half8 a = *(const half8*)op, b = *(const half8*)(op + 8);
        #pragma unroll
        for (int i = 0; i < 8; ++i) {
            acc[i]     += w[k] * (float)a[i];
            acc[8 + i] += w[k] * (float)b[i];
        }
    }
    float dot = 0.f;
    #pragma unroll
    for (int i = 0; i < 16; ++i) { acc[i] *= linv; dot += acc[i] * Wg[c * 16 + i]; }
    dot += __shfl_xor(dot, 1);
    dot += __shfl_xor(dot, 2);
    dot += __shfl_xor(dot, 4);
    dot += __shfl_xor(dot, 8);
    float g = 1.f / (1.f + __expf(-(dot + bg[0] + gb[0])));
    const float4* n4 = (const float4*)(Ng + (size_t)row * EMBED + c * 16);
    float4* o4 = (float4*)(out + (size_t)row * EMBED + c * 16);
    #pragma unroll
    for (int i = 0; i < 4; ++i) {
        float4 nn = n4[i];
        float4 res;
        res.x = acc[4*i+0] * g + nn.x * (1.f - g);
        res.y = acc[4*i+1] * g + nn.y * (1.f - g);
        res.z = acc[4*i+2] * g + nn.z * (1.f - g);
        res.w = acc[4*i+3] * g + nn.w * (1.f - g);
        o4[i] = res;
    }
}

extern "C" void kernel_launch(void* const* d_in, const int* in_sizes, int n_in,
                              void* d_out, int out_size, void* d_ws, size_t ws_size,
                              hipStream_t stream) {
    const float* M      = (const float*)d_in[0];
    const float* N      = (const float*)d_in[1];
    const float* Wgp    = (const float*)d_in[2];
    const float* bgp    = (const float*)d_in[3];
    const float* gbp    = (const float*)d_in[4];
    const int*   iseval = (const int*)d_in[5];
    float* out = (float*)d_out;

    int n = in_sizes[0] / EMBED;   // 8192
    short* MhG = (short*)d_ws;                          // n*256 fp16 = 4 MB
    short* MtG = MhG + (size_t)n * EMBED;               // n*256 fp16 = 4 MB
    short* Ofp = MtG + (size_t)n * EMBED;               // 3*n*256 fp16 = 12 MB
    float* MLm = (float*)(Ofp + (size_t)3 * n * EMBED); // 4n f32
    float* MLl = MLm + 4 * n;                           // 4n f32
    // ws required ~20.3 MB

    hipLaunchKernelGGL(prep, dim3(n / 16), dim3(NT), 0, stream, M, MhG, MtG);
    hipLaunchKernelGGL(attn, dim3((n / BQ) * 4), dim3(NT), 0, stream,
                       MhG, MtG, N, iseval, out, Ofp, MLm, MLl, n);
    hipLaunchKernelGGL(combine4, dim3(n / 16), dim3(NT), 0, stream,
                       out, Ofp, MLm, MLl, N, Wgp, bgp, gbp, out, n);
}

// Round 8
// 210.957 us; speedup vs baseline: 1.1394x; 1.1394x over previous
//
#include <hip/hip_runtime.h>

// AttentionMatcher R14: swapped QK^T -> in-register softmax (guide §B/T12).
// R12/R13 post-mortem: the serial chain's core cost is the S round-trip
// through LDS (SS write -> barrier -> read -> combine) + softmax state in
// LDS. R14 computes mfma(K,Q) so S[j][q] lands with q=lane&15: each lane
// owns a full q-row slice; row-reduce = 2x shfl_xor(16/32). No SS buffer,
// no MS/LS. P goes one-way through LDS ([64][80B] fp16) to PV waves (PV
// keeps d-quarter split so Mt L2 traffic stays 1x). Mh staged in LDS once
// per tile (16KB dbuf, XOR swizzle ^((j&7)<<4)) to avoid R13's 4x L2
// redundancy; T14 split staging (loads at phase top, ds_writes post-PV).
// Softmax in exp2 domain (Q pre-scaled by log2e; combine uses exp2f).
// out = gate * softmax(N M^T, diag<-0) M + (1-gate) * N,  n=8192, d=256, fp32.
//
// ws: MhG [n][256] fp16 row-major          (QK A-plane, staged to LDS)
//     MtG [n/32 tiles][256 d][32 j] fp16   (PV B-plane, transposed tile-major)
//     Ofp 3 fp16 partial O planes (splits 1..3); split-0 partial f32 in d_out
//     MLm/MLl [4][n] f32 running max (log2 domain) / sum per split.

constexpr int EMBED = 256;
constexpr int BQ = 64;
constexpr int BJ = 32;
constexpr int NT = 256;

constexpr int MH_OFF = 0;           // 2 x [32 j][512 B] swizzled = 32768
constexpr int MH_BUF = 16384;
constexpr int P_OFF  = 32768;       // [64 q][80 B] fp16 P tile = 5120
constexpr int A_OFF  = 37888;       // [64] f32 alpha = 256
constexpr int LDS_SZ = 38144;       // x2 blocks/CU = 76.3 KB (<160)

typedef _Float16 half8 __attribute__((ext_vector_type(8)));
typedef _Float16 half4v __attribute__((ext_vector_type(4)));
typedef float f32x4 __attribute__((ext_vector_type(4)));
typedef short short8v __attribute__((ext_vector_type(8)));

static __device__ __forceinline__ f32x4 mfma16(half8 a, half8 b, f32x4 c) {
    return __builtin_amdgcn_mfma_f32_16x16x32_f16(a, b, c, 0, 0, 0);
}
static __device__ __forceinline__ short f2h(float x) {
    return (short)__builtin_bit_cast(unsigned short, (_Float16)x);
}

// ---------- prep: fp16 row plane + fp16 transposed tile plane ----------
__global__ void prep(const float* __restrict__ M,
                     short* __restrict__ MhG, short* __restrict__ MtG) {
    __shared__ float L[16 * 260];
    const int r0 = blockIdx.x * 16;            // 16 M-rows per block
    const int t = threadIdx.x;
    const int pj = t >> 4, pc = (t & 15) * 16;
    {
        const float* src = M + (size_t)(r0 + pj) * EMBED + pc;
        float4 v[4];
        #pragma unroll
        for (int i = 0; i < 4; ++i) v[i] = ((const float4*)src)[i];
        short* hd = MhG + (size_t)(r0 + pj) * EMBED + pc;
        #pragma unroll
        for (int i = 0; i < 2; ++i) {
            float4 a = v[2 * i], b = v[2 * i + 1];
            short8v h;
            h[0]=f2h(a.x); h[1]=f2h(a.y); h[2]=f2h(a.z); h[3]=f2h(a.w);
            h[4]=f2h(b.x); h[5]=f2h(b.y); h[6]=f2h(b.z); h[7]=f2h(b.w);
            *(short8v*)(hd + 8 * i) = h;
        }
        #pragma unroll
        for (int i = 0; i < 4; ++i)
            *(float4*)(L + pj * 260 + pc + 4 * i) = v[i];
    }
    __syncthreads();
    {
        const int d = t;                        // 0..255
        const int tile = r0 >> 5, jh = (r0 >> 4) & 1;
        short* dst = MtG + (size_t)tile * (BJ * EMBED) + d * BJ + jh * 16;
        #pragma unroll
        for (int g2 = 0; g2 < 2; ++g2) {
            short8v w;
            #pragma unroll
            for (int e = 0; e < 8; ++e) w[e] = f2h(L[(g2 * 8 + e) * 260 + d]);
            *(short8v*)(dst + g2 * 8) = w;
        }
    }
}

// ---------- main split-j flash kernel: swapped QK, in-reg softmax ----------
__launch_bounds__(NT, 2)
__global__ void attn(const short* __restrict__ MhG, const short* __restrict__ MtG,
                     const float* __restrict__ Ng, const int* __restrict__ iseval_p,
                     float* __restrict__ O0out, short* __restrict__ Ofp,
                     float* __restrict__ MLm, float* __restrict__ MLl, int n)
{
    __shared__ __align__(16) char smem[LDS_SZ];

    const int t = threadIdx.x, lane = t & 63, wave = t >> 6;
    const int quad = lane >> 4, mn = lane & 15;
    // XCD swizzle: bid%8 -> XCD; 2 XCDs per split (R7 mapping).
    const int bid = blockIdx.x;
    const int s  = (bid & 7) >> 1;               // split 0..3
    const int qb = ((bid >> 3) << 1) | (bid & 1);// 0..127
    const int q0 = qb * BQ;
    const int jbase = s * (n >> 2);
    const int jb32 = jbase / BJ;
    const int ntiles = (n >> 2) / BJ;            // 64
    const int iseval = *iseval_p;
    const int qg = wave;                          // QK/softmax q-group (16 rows)
    const int dq = wave;                          // PV d-quarter
    const int qrow = q0 + qg * 16 + mn;           // this lane's softmax q-row
    const int swz = (mn & 7) << 4;                // Mh read swizzle (j&7 == mn&7)

    // staging roles: thread t stages Mh row sj, 64B chunk sc
    const int sj = t >> 3;                        // 0..31
    const int sc7 = t & 7;

    // ---- Q fragments (B-operand layout: col=q=mn, k=quad*8), scaled log2e ----
    const float L2E = 1.4426950408889634f;
    half8 Qf[8];
    {
        const float* np = Ng + (size_t)qrow * EMBED;
        #pragma unroll
        for (int kk = 0; kk < 8; ++kk) {
            const float* pp = np + kk * 32 + quad * 8;
            float4 a = *(const float4*)pp, b = *(const float4*)(pp + 4);
            half8 h;
            h[0]=(_Float16)(a.x*L2E); h[1]=(_Float16)(a.y*L2E);
            h[2]=(_Float16)(a.z*L2E); h[3]=(_Float16)(a.w*L2E);
            h[4]=(_Float16)(b.x*L2E); h[5]=(_Float16)(b.y*L2E);
            h[6]=(_Float16)(b.z*L2E); h[7]=(_Float16)(b.w*L2E);
            Qf[kk] = h;
        }
    }

    f32x4 O[4][4];
    #pragma unroll
    for (int qi = 0; qi < 4; ++qi)
        #pragma unroll
        for (int dt = 0; dt < 4; ++dt) O[qi][dt] = (f32x4){0.f, 0.f, 0.f, 0.f};

    float m_reg = -1e30f, l_reg = 0.f;   // per-q running max (log2) / sum

    // ---- prologue: stage Mh tile 0 into buf 0 ----
    {
        const short* src = MhG + (size_t)(jbase + sj) * EMBED + sc7 * 32;
        #pragma unroll
        for (int i = 0; i < 4; ++i) {
            short8v v = ((const short8v*)src)[i];
            int off = (sj * 512 + sc7 * 64 + i * 16) ^ ((sj & 7) << 4);
            *(short8v*)(smem + MH_OFF + off) = v;
        }
    }

    half8 Mtf[4];
    short8v stv[4];

    for (int tt = 0; tt < ntiles; ++tt) {
        const int p = tt & 1;
        __syncthreads();   // b1: Mh[p] writes (prev iter / prologue) visible

        // --- T14 stage-load for tile tt+1 (writes deferred to post-PV) ---
        if (tt + 1 < ntiles) {
            const short* src = MhG + (size_t)(jbase + (tt + 1) * BJ + sj) * EMBED + sc7 * 32;
            #pragma unroll
            for (int i = 0; i < 4; ++i) stv[i] = ((const short8v*)src)[i];
        }
        // --- Mt prefetch (this tile), consumed after b2 ---
        {
            const short* mtb = MtG + (size_t)(jb32 + tt) * (BJ * EMBED);
            #pragma unroll
            for (int dt = 0; dt < 4; ++dt)
                Mtf[dt] = *(const half8*)(mtb + (dq * 64 + dt * 16 + mn) * BJ + quad * 8);
        }

        // --- QK^T swapped: S[j][q] for this wave's 16 q x 32 j, K=256 ---
        f32x4 s0 = (f32x4){0,0,0,0}, s1 = (f32x4){0,0,0,0};
        {
            const int base = MH_OFF + p * MH_BUF;
            #pragma unroll
            for (int kk = 0; kk < 8; ++kk) {
                int o0 = (mn * 512 + kk * 64 + quad * 16) ^ swz;
                half8 k0 = *(const half8*)(smem + base + o0);          // j = mn
                half8 k1 = *(const half8*)(smem + base + 8192 + o0);   // j = 16+mn
                s0 = mfma16(k0, Qf[kk], s0);
                s1 = mfma16(k1, Qf[kk], s1);
            }
        }

        // --- in-register online softmax (lane owns q=qrow, j=quad*4+r, +16) ---
        {
            float sv[8] = {s0[0], s0[1], s0[2], s0[3], s1[0], s1[1], s1[2], s1[3]};
            if (iseval) {
                if (qrow == 0) {
                    #pragma unroll
                    for (int i = 0; i < 8; ++i) sv[i] = 0.f;
                }
            } else {
                int dj = qrow - (jbase + tt * BJ);
                #pragma unroll
                for (int i = 0; i < 4; ++i) {
                    if (dj == quad * 4 + i)      sv[i]     = 0.f;
                    if (dj == 16 + quad * 4 + i) sv[4 + i] = 0.f;
                }
            }
            float mx = sv[0];
            #pragma unroll
            for (int i = 1; i < 8; ++i) mx = fmaxf(mx, sv[i]);
            mx = fmaxf(mx, __shfl_xor(mx, 16));
            mx = fmaxf(mx, __shfl_xor(mx, 32));
            float m_new = fmaxf(m_reg, mx);
            float alpha = exp2f(m_reg - m_new);
            float pv8[8], ps = 0.f;
            #pragma unroll
            for (int i = 0; i < 8; ++i) { pv8[i] = exp2f(sv[i] - m_new); ps += pv8[i]; }
            ps += __shfl_xor(ps, 16);
            ps += __shfl_xor(ps, 32);
            m_reg = m_new;
            l_reg = l_reg * alpha + ps;
            // P row [qg*16+mn]: bytes [0..31]=j0..15, [32..63]=j16..31
            half4v h0, h1;
            #pragma unroll
            for (int i = 0; i < 4; ++i) { h0[i] = (_Float16)pv8[i]; h1[i] = (_Float16)pv8[4 + i]; }
            char* pb = smem + P_OFF + (qg * 16 + mn) * 80;
            *(half4v*)(pb + quad * 8)      = h0;
            *(half4v*)(pb + 32 + quad * 8) = h1;
            if (quad == 0)
                ((float*)(smem + A_OFF))[qg * 16 + mn] = alpha;
        }
        __syncthreads();   // b2: P/alpha visible to PV waves

        // --- PV: all 64 q x this wave's d-quarter, K=32 ---
        #pragma unroll
        for (int qi = 0; qi < 4; ++qi) {
            half8 pf = *(const half8*)(smem + P_OFF + (qi * 16 + mn) * 80 + quad * 16);
            f32x4 al = *(const f32x4*)(smem + A_OFF + (qi * 16 + quad * 4) * 4);
            #pragma unroll
            for (int dt = 0; dt < 4; ++dt) {
                f32x4 o = O[qi][dt];
                o[0] *= al[0]; o[1] *= al[1]; o[2] *= al[2]; o[3] *= al[3];
                O[qi][dt] = mfma16(pf, Mtf[dt], o);
            }
        }

        // --- deferred stage-writes for tile tt+1 into buf p^1 ---
        if (tt + 1 < ntiles) {
            #pragma unroll
            for (int i = 0; i < 4; ++i) {
                int off = (sj * 512 + sc7 * 64 + i * 16) ^ ((sj & 7) << 4);
                *(short8v*)(smem + MH_OFF + (p ^ 1) * MH_BUF + off) = stv[i];
            }
        }
        // Hazards: Mh[p^1] writes (here) vs next-iter QK reads: fenced by b1.
        // P/A writes (softmax t+1, post-b1(t+1)) vs PV(t) reads: b1 fences.
    }

    // ---- epilogue: partial O + (m,l) per split ----
    if (s == 0) {
        #pragma unroll
        for (int qi = 0; qi < 4; ++qi)
            #pragma unroll
            for (int dt = 0; dt < 4; ++dt) {
                int col = dq * 64 + dt * 16 + mn;
                #pragma unroll
                for (int r = 0; r < 4; ++r)
                    O0out[(size_t)(q0 + qi * 16 + quad * 4 + r) * EMBED + col] = O[qi][dt][r];
            }
    } else {
        short* dst = Ofp + (size_t)(s - 1) * n * EMBED;
        #pragma unroll
        for (int qi = 0; qi < 4; ++qi)
            #pragma unroll
            for (int dt = 0; dt < 4; ++dt) {
                int col = dq * 64 + dt * 16 + mn;
                #pragma unroll
                for (int r = 0; r < 4; ++r)
                    dst[(size_t)(q0 + qi * 16 + quad * 4 + r) * EMBED + col] = f2h(O[qi][dt][r]);
            }
    }
    if (lane < 16) {   // quad==0: one writer per q-row of this wave's group
        MLm[s * n + q0 + qg * 16 + mn] = m_reg;   // log2 domain
        MLl[s * n + q0 + qg * 16 + mn] = l_reg;
    }
}

// ---------- combine 4 partials + gate + blend (m in log2 domain) ----------
__global__ void combine4(const float* __restrict__ O0, const short* __restrict__ Ofp,
                         const float* __restrict__ MLm, const float* __restrict__ MLl,
                         const float* __restrict__ Ng, const float* __restrict__ Wg,
                         const float* __restrict__ bg, const float* __restrict__ gb,
                         float* __restrict__ out, int n)
{
    const int t = threadIdx.x;
    const int row = blockIdx.x * 16 + (t >> 4);
    const int c = t & 15;
    float ms[4], ls[4];
    #pragma unroll
    for (int k = 0; k < 4; ++k) { ms[k] = MLm[k * n + row]; ls[k] = MLl[k * n + row]; }
    float m = fmaxf(fmaxf(ms[0], ms[1]), fmaxf(ms[2], ms[3]));
    float w[4], lsum = 0.f;
    #pragma unroll
    for (int k = 0; k < 4; ++k) { w[k] = exp2f(ms[k] - m); lsum += w[k] * ls[k]; }
    float linv = 1.f / lsum;

    float acc[16];
    {
        const float4* o0 = (const float4*)(O0 + (size_t)row * EMBED + c * 16);
        #pragma unroll
        for (int i = 0; i < 4; ++i) {
            float4 v = o0[i];
            acc[4*i+0] = w[0] * v.x; acc[4*i+1] = w[0] * v.y;
            acc[4*i+2] = w[0] * v.z; acc[4*i+3] = w[0] * v.w;
        }
    }
    #pragma unroll
    for (int k = 1; k < 4; ++k) {
        const short* op = Ofp + (size_t)(k - 1) * n * EMBED + (size_t)row * EMBED + c * 16;
        half8 a = *(const half8*)op, b = *(const half8*)(op + 8);
        #pragma unroll
        for (int i = 0; i < 8; ++i) {
            acc[i]     += w[k] * (float)a[i];
            acc[8 + i] += w[k] * (float)b[i];
        }
    }
    float dot = 0.f;
    #pragma unroll
    for (int i = 0; i < 16; ++i) { acc[i] *= linv; dot += acc[i] * Wg[c * 16 + i]; }
    dot += __shfl_xor(dot, 1);
    dot += __shfl_xor(dot, 2);
    dot += __shfl_xor(dot, 4);
    dot += __shfl_xor(dot, 8);
    float g = 1.f / (1.f + __expf(-(dot + bg[0] + gb[0])));
    const float4* n4 = (const float4*)(Ng + (size_t)row * EMBED + c * 16);
    float4* o4 = (float4*)(out + (size_t)row * EMBED + c * 16);
    #pragma unroll
    for (int i = 0; i < 4; ++i) {
        float4 nn = n4[i];
        float4 res;
        res.x = acc[4*i+0] * g + nn.x * (1.f - g);
        res.y = acc[4*i+1] * g + nn.y * (1.f - g);
        res.z = acc[4*i+2] * g + nn.z * (1.f - g);
        res.w = acc[4*i+3] * g + nn.w * (1.f - g);
        o4[i] = res;
    }
}

extern "C" void kernel_launch(void* const* d_in, const int* in_sizes, int n_in,
                              void* d_out, int out_size, void* d_ws, size_t ws_size,
                              hipStream_t stream) {
    const float* M      = (const float*)d_in[0];
    const float* N      = (const float*)d_in[1];
    const float* Wgp    = (const float*)d_in[2];
    const float* bgp    = (const float*)d_in[3];
    const float* gbp    = (const float*)d_in[4];
    const int*   iseval = (const int*)d_in[5];
    float* out = (float*)d_out;

    int n = in_sizes[0] / EMBED;   // 8192
    short* MhG = (short*)d_ws;                          // n*256 fp16 = 4 MB
    short* MtG = MhG + (size_t)n * EMBED;               // n*256 fp16 = 4 MB
    short* Ofp = MtG + (size_t)n * EMBED;               // 3*n*256 fp16 = 12 MB
    float* MLm = (float*)(Ofp + (size_t)3 * n * EMBED); // 4n f32
    float* MLl = MLm + 4 * n;                           // 4n f32
    // ws required ~20.3 MB

    hipLaunchKernelGGL(prep, dim3(n / 16), dim3(NT), 0, stream, M, MhG, MtG);
    hipLaunchKernelGGL(attn, dim3((n / BQ) * 4), dim3(NT), 0, stream,
                       MhG, MtG, N, iseval, out, Ofp, MLm, MLl, n);
    hipLaunchKernelGGL(combine4, dim3(n / 16), dim3(NT), 0, stream,
                       out, Ofp, MLm, MLl, N, Wgp, bgp, gbp, out, n);
}